// Round 1
// baseline (132.886 us; speedup 1.0000x reference)
//
#include <hip/hip_runtime.h>
#include <hip/hip_bf16.h>

#define SS 7
#define NB 2
#define NC 20
#define NCELL (SS * SS)
#define NGT 32
#define CH (NB * 5 + NC)          // 30
#define NIMG 8192
#define LAMBDA_COORD 5.0f
#define LAMBDA_NOOBJ 0.5f
#define EPS_IOU 1e-6f

__global__ __launch_bounds__(128) void yolo_loss_kernel(
    const float* __restrict__ outputs,     // [N, 7, 7, 30]
    const float* __restrict__ gt_boxes,    // [N, 32, 4]  (cx, cy, w, h)
    const int*   __restrict__ gt_labels,   // [N, 32]
    float* __restrict__ out)               // [1]
{
    __shared__ float s_out[NCELL * CH];    // 5880 B: this image's activations
    __shared__ float s_gc[NGT][5];         // gx1, gy1, gx2, gy2, area
    __shared__ float s_graw[NGT][4];       // cx, cy, w, h (for matched-box terms)
    __shared__ float s_ce[NCELL];          // per-cell CE
    __shared__ unsigned int s_mask;        // 20-bit multihot label mask
    __shared__ float s_wsum[2];            // per-wave partial sums

    const int img = blockIdx.x;
    const int tid = threadIdx.x;

    if (tid == 0) s_mask = 0u;

    // ---- stage activations (coalesced: 1470 floats, 128 threads) ----
    const float* obase = outputs + (size_t)img * (NCELL * CH);
    for (int i = tid; i < NCELL * CH; i += 128) s_out[i] = obase[i];

    // ---- stage GT boxes + derived corners/areas ----
    if (tid < NGT) {
        const float* g = gt_boxes + ((size_t)img * NGT + tid) * 4;
        float cx = g[0], cy = g[1], w = g[2], h = g[3];
        s_graw[tid][0] = cx; s_graw[tid][1] = cy;
        s_graw[tid][2] = w;  s_graw[tid][3] = h;
        s_gc[tid][0] = cx - 0.5f * w;
        s_gc[tid][1] = cy - 0.5f * h;
        s_gc[tid][2] = cx + 0.5f * w;
        s_gc[tid][3] = cy + 0.5f * h;
        s_gc[tid][4] = w * h;
        int lab = gt_labels[(size_t)img * NGT + tid];
        atomicOr(&s_mask, 1u << lab);
    }
    __syncthreads();

    // ---- per-cell CE:  K*lse - sum_{c in mask} x_c ----
    if (tid < NCELL) {
        const float* cls = &s_out[tid * CH + NB * 5];
        float m = cls[0];
        #pragma unroll
        for (int c = 1; c < NC; ++c) m = fmaxf(m, cls[c]);
        float ssum = 0.f;
        #pragma unroll
        for (int c = 0; c < NC; ++c) ssum += __expf(cls[c] - m);
        float lse = m + __logf(ssum);
        unsigned int mask = s_mask;
        float sel = 0.f;
        #pragma unroll
        for (int c = 0; c < NC; ++c)
            if ((mask >> c) & 1u) sel += cls[c];
        s_ce[tid] = (float)__popc(mask) * lse - sel;
    }
    __syncthreads();

    // ---- per-(cell, box): IoU argmax over 32 GTs + loss terms ----
    float partial = 0.f;
    if (tid < NCELL * NB) {
        const int cell = tid >> 1;
        const int b    = tid & 1;
        const float* pb = &s_out[cell * CH + b * 5];
        const float cx = pb[0], cy = pb[1], w = pb[2], h = pb[3], conf = pb[4];
        const float px1 = cx - 0.5f * w, py1 = cy - 0.5f * h;
        const float px2 = cx + 0.5f * w, py2 = cy + 0.5f * h;
        const float parea = w * h;

        float best = -1.f;   // strict > update => first-index argmax (jnp semantics)
        int   bi   = 0;
        #pragma unroll 4
        for (int j = 0; j < NGT; ++j) {
            float iw = fminf(px2, s_gc[j][2]) - fmaxf(px1, s_gc[j][0]);
            iw = fmaxf(iw, 0.f);
            float ih = fminf(py2, s_gc[j][3]) - fmaxf(py1, s_gc[j][1]);
            ih = fmaxf(ih, 0.f);
            float inter = iw * ih;
            float iou = inter / (parea + s_gc[j][4] - inter + EPS_IOU);
            if (iou > best) { best = iou; bi = j; }
        }

        if (best > 0.f) {
            const float mx = s_graw[bi][0], my = s_graw[bi][1];
            const float mw = s_graw[bi][2], mh = s_graw[bi][3];
            const float dw = sqrtf(w) - sqrtf(mw);
            const float dh = sqrtf(h) - sqrtf(mh);
            const float loc = LAMBDA_COORD *
                ((cx - mx) * (cx - mx) + (cy - my) * (cy - my) + dw * dw + dh * dh);
            const float co = (conf - best) * (conf - best);
            partial = loc + co + s_ce[cell];
        } else {
            partial = LAMBDA_NOOBJ * conf * conf;
        }
    }

    // ---- block reduce (2 waves) + global atomic ----
    #pragma unroll
    for (int off = 32; off > 0; off >>= 1)
        partial += __shfl_down(partial, off);
    if ((tid & 63) == 0) s_wsum[tid >> 6] = partial;
    __syncthreads();
    if (tid == 0)
        atomicAdd(out, (s_wsum[0] + s_wsum[1]) * (1.0f / (float)NIMG));
}

extern "C" void kernel_launch(void* const* d_in, const int* in_sizes, int n_in,
                              void* d_out, int out_size, void* d_ws, size_t ws_size,
                              hipStream_t stream) {
    const float* outputs   = (const float*)d_in[0];
    const float* gt_boxes  = (const float*)d_in[1];
    const int*   gt_labels = (const int*)d_in[2];
    float* out = (float*)d_out;

    hipMemsetAsync(out, 0, sizeof(float), stream);
    yolo_loss_kernel<<<NIMG, 128, 0, stream>>>(outputs, gt_boxes, gt_labels, out);
}

// Round 2
// 39.198 us; speedup vs baseline: 3.3901x; 3.3901x over previous
//
#include <hip/hip_runtime.h>
#include <hip/hip_bf16.h>

#define SS 7
#define NB 2
#define NC 20
#define NCELL 49
#define NGT 32
#define CH 30
#define NIMG 8192
#define NTOT (NIMG * NCELL)        // 401408 = 1568 * 256 exactly
#define NBLK 1568
#define LAMBDA_COORD 5.0f
#define LAMBDA_NOOBJ 0.5f
#define EPS_IOU 1e-6f

// One thread per (image, cell). Computes CE (once) + both boxes' IoU argmax
// and loss terms. No barriers in the hot path; GT reads are wave-broadcast
// L1 hits (49 threads/image share the same 32 float4s).
__global__ __launch_bounds__(256, 4) void yolo_main_kernel(
    const float* __restrict__ outputs,     // [N, 49, 30]
    const float* __restrict__ gt_boxes,    // [N, 32, 4] (cx, cy, w, h)
    const int*   __restrict__ gt_labels,   // [N, 32]
    float* __restrict__ partials)          // [NBLK]
{
    const unsigned int t   = blockIdx.x * 256 + threadIdx.x;   // cell id, < NTOT
    const unsigned int img = t / NCELL;                        // magic-mul div

    // outputs for this cell: 30 floats at byte offset t*120 (8B aligned)
    const float2* f2 = reinterpret_cast<const float2*>(outputs) + (size_t)t * 15;

    // ---- label multihot mask (broadcast loads, L1-resident) ----
    const int* lab = gt_labels + (size_t)img * NGT;
    unsigned int mask = 0u;
    #pragma unroll
    for (int j = 0; j < NGT; ++j) mask |= 1u << lab[j];

    // ---- CE first so class registers die before the box loop ----
    float cls[NC];
    #pragma unroll
    for (int k = 0; k < 10; ++k) {
        float2 v = f2[5 + k];
        cls[2 * k] = v.x; cls[2 * k + 1] = v.y;
    }
    float mx0 = cls[0];
    #pragma unroll
    for (int c = 1; c < NC; ++c) mx0 = fmaxf(mx0, cls[c]);
    float ssum = 0.f;
    #pragma unroll
    for (int c = 0; c < NC; ++c) ssum += __expf(cls[c] - mx0);
    float lse = mx0 + __logf(ssum);
    float sel = 0.f;
    #pragma unroll
    for (int c = 0; c < NC; ++c)
        if ((mask >> c) & 1u) sel += cls[c];
    const float ce = (float)__popc(mask) * lse - sel;

    // ---- box registers ----
    float2 q0 = f2[0], q1 = f2[1], q2 = f2[2], q3 = f2[3], q4 = f2[4];
    const float cx0 = q0.x, cy0 = q0.y, w0 = q1.x, h0 = q1.y, cf0 = q2.x;
    const float cx1 = q2.y, cy1 = q3.x, w1 = q3.y, h1 = q4.x, cf1 = q4.y;

    const float px1_0 = fmaf(w0, -0.5f, cx0), py1_0 = fmaf(h0, -0.5f, cy0);
    const float px2_0 = fmaf(w0,  0.5f, cx0), py2_0 = fmaf(h0,  0.5f, cy0);
    const float px1_1 = fmaf(w1, -0.5f, cx1), py1_1 = fmaf(h1, -0.5f, cy1);
    const float px2_1 = fmaf(w1,  0.5f, cx1), py2_1 = fmaf(h1,  0.5f, cy1);
    const float pa0 = w0 * h0, pa1 = w1 * h1;

    // ---- IoU argmax over 32 GTs, both boxes per iteration ----
    const float4* gc = reinterpret_cast<const float4*>(gt_boxes) + (size_t)img * NGT;
    float best0 = -1.f, best1 = -1.f;
    int   bi0 = 0, bi1 = 0;
    #pragma unroll 4
    for (int j = 0; j < NGT; ++j) {
        float4 g = gc[j];                       // cx, cy, w, h (broadcast)
        const float gx1 = fmaf(g.z, -0.5f, g.x), gy1 = fmaf(g.w, -0.5f, g.y);
        const float gx2 = fmaf(g.z,  0.5f, g.x), gy2 = fmaf(g.w,  0.5f, g.y);
        const float ga  = g.z * g.w;

        float iw0 = fmaxf(fminf(px2_0, gx2) - fmaxf(px1_0, gx1), 0.f);
        float ih0 = fmaxf(fminf(py2_0, gy2) - fmaxf(py1_0, gy1), 0.f);
        float in0 = iw0 * ih0;
        float iou0 = __fdividef(in0, pa0 + ga - in0 + EPS_IOU);
        if (iou0 > best0) { best0 = iou0; bi0 = j; }

        float iw1 = fmaxf(fminf(px2_1, gx2) - fmaxf(px1_1, gx1), 0.f);
        float ih1 = fmaxf(fminf(py2_1, gy2) - fmaxf(py1_1, gy1), 0.f);
        float in1 = iw1 * ih1;
        float iou1 = __fdividef(in1, pa1 + ga - in1 + EPS_IOU);
        if (iou1 > best1) { best1 = iou1; bi1 = j; }
    }

    // ---- loss terms ----
    float partial;
    {
        float term0, term1;
        if (best0 > 0.f) {
            float4 g = gc[bi0];                 // L1 hit
            float dx = cx0 - g.x, dy = cy0 - g.y;
            float dw = sqrtf(w0) - sqrtf(g.z), dh = sqrtf(h0) - sqrtf(g.w);
            term0 = LAMBDA_COORD * (dx * dx + dy * dy + dw * dw + dh * dh)
                  + (cf0 - best0) * (cf0 - best0) + ce;
        } else {
            term0 = LAMBDA_NOOBJ * cf0 * cf0;
        }
        if (best1 > 0.f) {
            float4 g = gc[bi1];
            float dx = cx1 - g.x, dy = cy1 - g.y;
            float dw = sqrtf(w1) - sqrtf(g.z), dh = sqrtf(h1) - sqrtf(g.w);
            term1 = LAMBDA_COORD * (dx * dx + dy * dy + dw * dw + dh * dh)
                  + (cf1 - best1) * (cf1 - best1) + ce;
        } else {
            term1 = LAMBDA_NOOBJ * cf1 * cf1;
        }
        partial = term0 + term1;
    }

    // ---- block reduce: wave shuffle -> 4 LDS words -> 1 float per block ----
    #pragma unroll
    for (int off = 32; off > 0; off >>= 1)
        partial += __shfl_down(partial, off);
    __shared__ float s_w[4];
    const int tid = threadIdx.x;
    if ((tid & 63) == 0) s_w[tid >> 6] = partial;
    __syncthreads();
    if (tid == 0)
        partials[blockIdx.x] = s_w[0] + s_w[1] + s_w[2] + s_w[3];
}

__global__ __launch_bounds__(256) void yolo_reduce_kernel(
    const float* __restrict__ partials, float* __restrict__ out)
{
    float s = 0.f;
    for (int i = threadIdx.x; i < NBLK; i += 256) s += partials[i];
    #pragma unroll
    for (int off = 32; off > 0; off >>= 1)
        s += __shfl_down(s, off);
    __shared__ float s_w[4];
    const int tid = threadIdx.x;
    if ((tid & 63) == 0) s_w[tid >> 6] = s;
    __syncthreads();
    if (tid == 0)
        out[0] = (s_w[0] + s_w[1] + s_w[2] + s_w[3]) * (1.0f / (float)NIMG);
}

extern "C" void kernel_launch(void* const* d_in, const int* in_sizes, int n_in,
                              void* d_out, int out_size, void* d_ws, size_t ws_size,
                              hipStream_t stream) {
    const float* outputs   = (const float*)d_in[0];
    const float* gt_boxes  = (const float*)d_in[1];
    const int*   gt_labels = (const int*)d_in[2];
    float* out      = (float*)d_out;
    float* partials = (float*)d_ws;          // NBLK floats = 6.3 KB

    yolo_main_kernel<<<NBLK, 256, 0, stream>>>(outputs, gt_boxes, gt_labels, partials);
    yolo_reduce_kernel<<<1, 256, 0, stream>>>(partials, out);
}

// Round 3
// 32.753 us; speedup vs baseline: 4.0573x; 1.1968x over previous
//
#include <hip/hip_runtime.h>
#include <hip/hip_bf16.h>

#define NC 20
#define NCELL 49
#define NGT 32
#define NIMG 8192
#define NTOT (NIMG * NCELL)        // 401408 = 1568 * 256 exactly
#define NBLK 1568
#define MAXIMG 7                   // images spanned by 256 consecutive cells
#define LAMBDA_COORD 5.0f
#define LAMBDA_NOOBJ 0.5f
#define EPS_IOU 1e-6f

// s_gt per-GT record, stride 10 floats (40 B, every float2 pair 8B-aligned):
//   0:x1  1:y1  2:x2  3:y2  4:area  5:sqrt(w)  6:sqrt(h)  7:cx  8:cy  9:pad
__global__ __launch_bounds__(256, 4) void yolo_main_kernel(
    const float* __restrict__ outputs,     // [N, 49, 30]
    const float* __restrict__ gt_boxes,    // [N, 32, 4]
    const int*   __restrict__ gt_labels,   // [N, 32]
    float* __restrict__ partials)          // [NBLK]
{
    __shared__ float4  s_act4[1920];               // 30720 B: 256 cells x 30 floats
    __shared__ float   s_gt[MAXIMG * NGT * 10];    // 8960 B
    __shared__ unsigned s_mask[MAXIMG];
    __shared__ float   s_w[4];

    const int tid = threadIdx.x;
    const unsigned base   = blockIdx.x * 256u;
    const unsigned img_lo = base / NCELL;

    if (tid < MAXIMG) s_mask[tid] = 0u;
    __syncthreads();

    // ---- stage activations: coalesced float4, linear copy ----
    const float4* src = reinterpret_cast<const float4*>(outputs) + (size_t)base * 30 / 4;
    #pragma unroll
    for (int k = 0; k < 8; ++k) {
        int i = tid + k * 256;
        if (i < 1920) s_act4[i] = src[i];
    }

    // ---- stage GT records (corners/area/sqrt precomputed once per GT) ----
    if (tid < MAXIMG * NGT) {
        const unsigned g   = tid >> 5;
        const unsigned j   = tid & 31u;
        const unsigned img = img_lo + g;
        if (img < NIMG) {
            float4 b = reinterpret_cast<const float4*>(gt_boxes)[(size_t)img * NGT + j];
            float* d = &s_gt[tid * 10];
            d[0] = fmaf(b.z, -0.5f, b.x);
            d[1] = fmaf(b.w, -0.5f, b.y);
            d[2] = fmaf(b.z,  0.5f, b.x);
            d[3] = fmaf(b.w,  0.5f, b.y);
            d[4] = b.z * b.w;
            d[5] = sqrtf(b.z);
            d[6] = sqrtf(b.w);
            d[7] = b.x;
            d[8] = b.y;
            int lab = gt_labels[(size_t)img * NGT + j];
            atomicOr(&s_mask[g], 1u << lab);
        }
    }
    __syncthreads();

    // ---- per-thread compute: one (image, cell) ----
    const unsigned t_img = (base + (unsigned)tid) / NCELL;
    const unsigned rel   = t_img - img_lo;
    const unsigned mask  = s_mask[rel];
    const float2* a2 = reinterpret_cast<const float2*>(s_act4) + tid * 15;

    // CE first so class registers die before the box loop
    float cls[NC];
    #pragma unroll
    for (int k = 0; k < 10; ++k) {
        float2 v = a2[5 + k];
        cls[2 * k] = v.x; cls[2 * k + 1] = v.y;
    }
    float mx0 = cls[0];
    #pragma unroll
    for (int c = 1; c < NC; ++c) mx0 = fmaxf(mx0, cls[c]);
    float ssum = 0.f;
    #pragma unroll
    for (int c = 0; c < NC; ++c) ssum += __expf(cls[c] - mx0);
    const float lse = mx0 + __logf(ssum);
    float sel = 0.f;
    #pragma unroll
    for (int c = 0; c < NC; ++c)
        if ((mask >> c) & 1u) sel += cls[c];
    const float ce = (float)__popc(mask) * lse - sel;

    // box registers
    float2 q0 = a2[0], q1 = a2[1], q2 = a2[2], q3 = a2[3], q4 = a2[4];
    const float cx0 = q0.x, cy0 = q0.y, w0 = q1.x, h0 = q1.y, cf0 = q2.x;
    const float cx1 = q2.y, cy1 = q3.x, w1 = q3.y, h1 = q4.x, cf1 = q4.y;
    const float px1_0 = fmaf(w0, -0.5f, cx0), py1_0 = fmaf(h0, -0.5f, cy0);
    const float px2_0 = fmaf(w0,  0.5f, cx0), py2_0 = fmaf(h0,  0.5f, cy0);
    const float px1_1 = fmaf(w1, -0.5f, cx1), py1_1 = fmaf(h1, -0.5f, cy1);
    const float px2_1 = fmaf(w1,  0.5f, cx1), py2_1 = fmaf(h1,  0.5f, cy1);
    const float pa0e = w0 * h0 + EPS_IOU, pa1e = w1 * h1 + EPS_IOU;

    // divide-free IoU argmax: compare in_j * bden > bin * den_j
    // (den = pa + ga + eps - in > 0 always; init -1/1 so j=0 always wins
    //  => strict-> first-index argmax, matching jnp)
    const float* gtb = &s_gt[rel * NGT * 10];
    float bin0 = -1.f, bden0 = 1.f, bin1 = -1.f, bden1 = 1.f;
    int bi0 = 0, bi1 = 0;
    #pragma unroll 8
    for (int j = 0; j < NGT; ++j) {
        const float* gj = gtb + j * 10;
        const float2 p01 = *reinterpret_cast<const float2*>(gj);       // x1, y1
        const float2 p23 = *reinterpret_cast<const float2*>(gj + 2);   // x2, y2
        const float  ga  = gj[4];

        float iw0 = fmaxf(fminf(px2_0, p23.x) - fmaxf(px1_0, p01.x), 0.f);
        float ih0 = fmaxf(fminf(py2_0, p23.y) - fmaxf(py1_0, p01.y), 0.f);
        float in0 = iw0 * ih0;
        float den0 = (pa0e + ga) - in0;
        if (in0 * bden0 > bin0 * den0) { bin0 = in0; bden0 = den0; bi0 = j; }

        float iw1 = fmaxf(fminf(px2_1, p23.x) - fmaxf(px1_1, p01.x), 0.f);
        float ih1 = fmaxf(fminf(py2_1, p23.y) - fmaxf(py1_1, p01.y), 0.f);
        float in1 = iw1 * ih1;
        float den1 = (pa1e + ga) - in1;
        if (in1 * bden1 > bin1 * den1) { bin1 = in1; bden1 = den1; bi1 = j; }
    }

    // loss terms (division happens twice total, not 64x)
    float term0, term1;
    if (bin0 > 0.f) {
        const float* gj = gtb + bi0 * 10;
        const float2 asw = *reinterpret_cast<const float2*>(gj + 4);   // area, sqw
        const float2 shc = *reinterpret_cast<const float2*>(gj + 6);   // sqh, cx
        const float2 cyp = *reinterpret_cast<const float2*>(gj + 8);   // cy, pad
        const float iou = __fdividef(bin0, bden0);
        const float dx = cx0 - shc.y, dy = cy0 - cyp.x;
        const float dw = sqrtf(w0) - asw.y, dh = sqrtf(h0) - shc.x;
        term0 = LAMBDA_COORD * (dx * dx + dy * dy + dw * dw + dh * dh)
              + (cf0 - iou) * (cf0 - iou) + ce;
    } else {
        term0 = LAMBDA_NOOBJ * cf0 * cf0;
    }
    if (bin1 > 0.f) {
        const float* gj = gtb + bi1 * 10;
        const float2 asw = *reinterpret_cast<const float2*>(gj + 4);
        const float2 shc = *reinterpret_cast<const float2*>(gj + 6);
        const float2 cyp = *reinterpret_cast<const float2*>(gj + 8);
        const float iou = __fdividef(bin1, bden1);
        const float dx = cx1 - shc.y, dy = cy1 - cyp.x;
        const float dw = sqrtf(w1) - asw.y, dh = sqrtf(h1) - shc.x;
        term1 = LAMBDA_COORD * (dx * dx + dy * dy + dw * dw + dh * dh)
              + (cf1 - iou) * (cf1 - iou) + ce;
    } else {
        term1 = LAMBDA_NOOBJ * cf1 * cf1;
    }
    float partial = term0 + term1;

    // ---- block reduce -> 1 float per block ----
    #pragma unroll
    for (int off = 32; off > 0; off >>= 1)
        partial += __shfl_down(partial, off);
    if ((tid & 63) == 0) s_w[tid >> 6] = partial;
    __syncthreads();
    if (tid == 0)
        partials[blockIdx.x] = s_w[0] + s_w[1] + s_w[2] + s_w[3];
}

__global__ __launch_bounds__(256) void yolo_reduce_kernel(
    const float* __restrict__ partials, float* __restrict__ out)
{
    float s = 0.f;
    for (int i = threadIdx.x; i < NBLK; i += 256) s += partials[i];
    #pragma unroll
    for (int off = 32; off > 0; off >>= 1)
        s += __shfl_down(s, off);
    __shared__ float s_w[4];
    const int tid = threadIdx.x;
    if ((tid & 63) == 0) s_w[tid >> 6] = s;
    __syncthreads();
    if (tid == 0)
        out[0] = (s_w[0] + s_w[1] + s_w[2] + s_w[3]) * (1.0f / (float)NIMG);
}

extern "C" void kernel_launch(void* const* d_in, const int* in_sizes, int n_in,
                              void* d_out, int out_size, void* d_ws, size_t ws_size,
                              hipStream_t stream) {
    const float* outputs   = (const float*)d_in[0];
    const float* gt_boxes  = (const float*)d_in[1];
    const int*   gt_labels = (const int*)d_in[2];
    float* out      = (float*)d_out;
    float* partials = (float*)d_ws;          // NBLK floats = 6.3 KB

    yolo_main_kernel<<<NBLK, 256, 0, stream>>>(outputs, gt_boxes, gt_labels, partials);
    yolo_reduce_kernel<<<1, 256, 0, stream>>>(partials, out);
}